// Round 1
// baseline (794.608 us; speedup 1.0000x reference)
//
#include <hip/hip_runtime.h>
#include <cstdint>

// Problem constants (b=16, c=384, H=W=48, heads=8, d=48, n=2304)
#define B_   16
#define C_   384
#define N_   2304
#define H_   8
#define D_   48

// ---------------------------------------------------------------------------
// GEMM: O[b][m][n] = bias[m] + sum_k A[b][k][m] * X[b][k][n]
// A is K x M (lda = M), X is K x N (row stride N), O is M x N.
// Tiles: 64x64 output, K-tile 16, 256 threads, 4x4 per thread. All dims
// divide evenly for our two uses (M in {1152,384}, N=2304, K=384).
// ---------------------------------------------------------------------------
__global__ __launch_bounds__(256) void gemm_atx(
    const float* __restrict__ A, long aStride, int lda,
    const float* __restrict__ X, long xStride,
    float* __restrict__ O, long oStride,
    const float* __restrict__ bias, int K, int N)
{
    __shared__ float As[16][64];
    __shared__ float Bs[16][64];
    const int b = blockIdx.z;
    A += (long)b * aStride;
    X += (long)b * xStride;
    O += (long)b * oStride;
    const int m0 = blockIdx.x * 64;
    const int n0 = blockIdx.y * 64;
    const int t  = threadIdx.x;
    const int tx = t & 15, ty = t >> 4;

    float acc[4][4] = {};

    for (int k0 = 0; k0 < K; k0 += 16) {
#pragma unroll
        for (int r = 0; r < 4; ++r) {
            int idx = t + 256 * r;           // 0..1023
            int kk = idx >> 6, col = idx & 63;
            As[kk][col] = A[(long)(k0 + kk) * lda + m0 + col];
            Bs[kk][col] = X[(long)(k0 + kk) * N + n0 + col];
        }
        __syncthreads();
#pragma unroll
        for (int kk = 0; kk < 16; ++kk) {
            float av[4], bv[4];
#pragma unroll
            for (int i = 0; i < 4; ++i) av[i] = As[kk][ty * 4 + i];
#pragma unroll
            for (int j = 0; j < 4; ++j) bv[j] = Bs[kk][tx * 4 + j];
#pragma unroll
            for (int i = 0; i < 4; ++i)
#pragma unroll
                for (int j = 0; j < 4; ++j)
                    acc[i][j] += av[i] * bv[j];
        }
        __syncthreads();
    }

#pragma unroll
    for (int i = 0; i < 4; ++i) {
        int m = m0 + ty * 4 + i;
        float bb = bias ? bias[m] : 0.0f;
        float4 v = make_float4(acc[i][0] + bb, acc[i][1] + bb,
                               acc[i][2] + bb, acc[i][3] + bb);
        *reinterpret_cast<float4*>(&O[(long)m * N + n0 + tx * 4]) = v;
    }
}

// ---------------------------------------------------------------------------
// Column norms over n: norms[b][ch] = max(sqrt(sum_n qkv[b][ch][n]^2), eps)
// ch in [0,768): 0..383 = q channels, 384..767 = k channels.
// ---------------------------------------------------------------------------
__global__ __launch_bounds__(256) void colnorm_kernel(
    const float* __restrict__ qkv, float* __restrict__ norms)
{
    const int b = blockIdx.y;
    const int ch = blockIdx.x;               // 0..767
    const float* row = qkv + ((long)b * 1152 + ch) * N_;
    float s = 0.0f;
    for (int i = threadIdx.x; i < N_; i += 256) {
        float v = row[i];
        s += v * v;
    }
    __shared__ float red[256];
    red[threadIdx.x] = s;
    __syncthreads();
    for (int off = 128; off > 0; off >>= 1) {
        if (threadIdx.x < off) red[threadIdx.x] += red[threadIdx.x + off];
        __syncthreads();
    }
    if (threadIdx.x == 0)
        norms[(long)b * 768 + ch] = fmaxf(sqrtf(red[0]), 1e-12f);
}

// ---------------------------------------------------------------------------
// Per-(b,h): S[p][q] = temp[h] * (K_p . Q_q) / (nk[p]*nq[q]); softmax rows;
// then fold: W2[b][h*48+p][j] = sum_q S[p][q] * w_out[(h*48+q)*384 + j].
// One block per (b,h); 256 threads; each thread owns a 3x3 (p,q) tile.
// ---------------------------------------------------------------------------
__global__ __launch_bounds__(256) void attn_fold_kernel(
    const float* __restrict__ qkv,   // [b][1152][N]
    const float* __restrict__ norms, // [b][768]
    const float* __restrict__ temp,  // [8]
    const float* __restrict__ w_out, // [384][384]
    float* __restrict__ W2)          // [b][384][384]
{
    const int h = blockIdx.x;
    const int b = blockIdx.y;

    __shared__ float ks[48][65];   // +1 pad: ty-strided row reads hit distinct banks
    __shared__ float qs[48][65];
    __shared__ float S[48][49];

    const float* qbase = qkv + ((long)b * 1152 + h * 48) * N_;
    const float* kbase = qkv + ((long)b * 1152 + 384 + h * 48) * N_;

    const int t  = threadIdx.x;
    const int p0 = (t >> 4) * 3;   // 16 groups * 3 = 48
    const int q0 = (t & 15) * 3;

    float acc[3][3] = {};

    for (int n0 = 0; n0 < N_; n0 += 64) {
#pragma unroll
        for (int r = 0; r < 12; ++r) {
            int idx = t + 256 * r;           // 0..3071
            int row = idx >> 6, col = idx & 63;
            qs[row][col] = qbase[(long)row * N_ + n0 + col];
            ks[row][col] = kbase[(long)row * N_ + n0 + col];
        }
        __syncthreads();
#pragma unroll 8
        for (int nn = 0; nn < 64; ++nn) {
            float a0 = ks[p0 + 0][nn], a1 = ks[p0 + 1][nn], a2 = ks[p0 + 2][nn];
            float c0 = qs[q0 + 0][nn], c1 = qs[q0 + 1][nn], c2 = qs[q0 + 2][nn];
            acc[0][0] += a0 * c0; acc[0][1] += a0 * c1; acc[0][2] += a0 * c2;
            acc[1][0] += a1 * c0; acc[1][1] += a1 * c1; acc[1][2] += a1 * c2;
            acc[2][0] += a2 * c0; acc[2][1] += a2 * c1; acc[2][2] += a2 * c2;
        }
        __syncthreads();
    }

    const float th = temp[h];
    const float* nq = norms + (long)b * 768;        // q norms: [0..383]
    const float* nk = nq + 384;                     // k norms: [384..767]
#pragma unroll
    for (int i = 0; i < 3; ++i)
#pragma unroll
        for (int j = 0; j < 3; ++j)
            S[p0 + i][q0 + j] = acc[i][j] * th /
                (nk[h * 48 + p0 + i] * nq[h * 48 + q0 + j]);
    __syncthreads();

    // softmax over q (rows p), threads 0..47 each own one row
    if (t < 48) {
        float m = -1e30f;
#pragma unroll 8
        for (int q = 0; q < 48; ++q) m = fmaxf(m, S[t][q]);
        float ssum = 0.0f;
#pragma unroll 8
        for (int q = 0; q < 48; ++q) {
            float e = __expf(S[t][q] - m);
            S[t][q] = e;
            ssum += e;
        }
        float inv = 1.0f / ssum;
#pragma unroll 8
        for (int q = 0; q < 48; ++q) S[t][q] *= inv;
    }
    __syncthreads();

    // fold attn into w_out: 48*384 outputs, 72 per thread
    float* W2b = W2 + ((long)b * 384 + h * 48) * 384;
    for (int idx = t; idx < 48 * 384; idx += 256) {
        int p = idx / 384, j = idx - p * 384;
        float s = 0.0f;
#pragma unroll 8
        for (int q = 0; q < 48; ++q)
            s += S[p][q] * w_out[(long)(h * 48 + q) * 384 + j];
        W2b[(long)p * 384 + j] = s;
    }
}

// ---------------------------------------------------------------------------
extern "C" void kernel_launch(void* const* d_in, const int* in_sizes, int n_in,
                              void* d_out, int out_size, void* d_ws, size_t ws_size,
                              hipStream_t stream) {
    const float* x      = (const float*)d_in[0];  // [16][384][2304]
    const float* w_qkv  = (const float*)d_in[1];  // [384][1152]
    const float* temp   = (const float*)d_in[2];  // [8]
    const float* w_out  = (const float*)d_in[3];  // [384][384]
    const float* b_out  = (const float*)d_in[4];  // [384]
    float* out = (float*)d_out;                   // [16][384][2304]

    // workspace layout
    float* qkv   = (float*)d_ws;                          // 16*1152*2304 f32 (~170 MB)
    float* norms = qkv + (size_t)B_ * 1152 * N_;          // 16*768
    float* W2    = norms + (size_t)B_ * 768;              // 16*384*384 (~9.4 MB)

    // 1) qkv[b][cc][n] = sum_c w_qkv[c][cc] * x[b][c][n]
    gemm_atx<<<dim3(1152 / 64, N_ / 64, B_), 256, 0, stream>>>(
        w_qkv, 0L, 1152,
        x, (long)C_ * N_,
        qkv, (long)1152 * N_,
        nullptr, C_, N_);

    // 2) token-axis L2 norms for q and k channels
    colnorm_kernel<<<dim3(768, B_), 256, 0, stream>>>(qkv, norms);

    // 3) attention + softmax + fold into output projection
    attn_fold_kernel<<<dim3(H_, B_), 256, 0, stream>>>(
        qkv, norms, temp, w_out, W2);

    // 4) out[b][j][n] = b_out[j] + sum_c W2[b][c][j] * v[b][c][n]
    gemm_atx<<<dim3(384 / 64, N_ / 64, B_), 256, 0, stream>>>(
        W2, (long)384 * 384, 384,
        qkv + (size_t)768 * N_, (long)1152 * N_,
        out, (long)C_ * N_,
        b_out, C_, N_);
}

// Round 2
// 222.084 us; speedup vs baseline: 3.5780x; 3.5780x over previous
//
#include <hip/hip_runtime.h>
#include <cstdint>

typedef __attribute__((ext_vector_type(8))) short short8;
typedef __attribute__((ext_vector_type(4))) float f32x4;
typedef unsigned int u32;
typedef unsigned short u16;

#define NTOK 2304
#define KDIM 384

__device__ __forceinline__ u16 f2bf(float f) {
    u32 u = __builtin_bit_cast(u32, f);
    u32 r = (u + 0x7FFFu + ((u >> 16) & 1u)) >> 16;
    return (u16)r;
}
__device__ __forceinline__ float bf2f(u32 h) {
    u32 u = h << 16;
    return __builtin_bit_cast(float, u);
}

// ---------------------------------------------------------------------------
// Transpose + convert: src f32 [K=384][Csz] -> dst bf16 [Csz][384], rows
// XOR-swizzled in 16B chunks: byte' = byte ^ ((row&7)<<4). 64x64 tiles.
// ---------------------------------------------------------------------------
__global__ __launch_bounds__(256) void transpose_f32_to_bf16swz(
    const float* __restrict__ src, long sBatch, int Csz,
    u16* __restrict__ dst, long dBatch)
{
    __shared__ float tile[64][65];
    const int b = blockIdx.z;
    const int c0 = blockIdx.x * 64;   // output-row dim
    const int k0 = blockIdx.y * 64;   // contraction dim (src rows)
    src += (long)b * sBatch;
    dst += (long)b * dBatch;
    const int t = threadIdx.x;
    const int rr = t >> 2, cc4 = (t & 3) * 16;

    const float* srow = src + (long)(k0 + rr) * Csz + c0 + cc4;
#pragma unroll
    for (int i = 0; i < 4; ++i) {
        float4 v = *(const float4*)(srow + i * 4);
        tile[rr][cc4 + i*4 + 0] = v.x;
        tile[rr][cc4 + i*4 + 1] = v.y;
        tile[rr][cc4 + i*4 + 2] = v.z;
        tile[rr][cc4 + i*4 + 3] = v.w;
    }
    __syncthreads();
    char* drow = (char*)dst + (long)(c0 + rr) * (KDIM * 2);
    const int sw = (rr & 7) << 4;
#pragma unroll
    for (int half = 0; half < 2; ++half) {
        u32 pk[4];
#pragma unroll
        for (int i = 0; i < 4; ++i) {
            float v0 = tile[cc4 + half*8 + 2*i][rr];
            float v1 = tile[cc4 + half*8 + 2*i + 1][rr];
            pk[i] = (u32)f2bf(v0) | ((u32)f2bf(v1) << 16);
        }
        uint4 q; q.x = pk[0]; q.y = pk[1]; q.z = pk[2]; q.w = pk[3];
        const int inrow = (k0 + cc4 + half*8) * 2;
        *(uint4*)(drow + (inrow ^ sw)) = q;
    }
}

// ---------------------------------------------------------------------------
// Transpose v (bf16 src): qkv rows 768..1151 [384][2304] -> vT [2304][384] swz
// ---------------------------------------------------------------------------
__global__ __launch_bounds__(256) void transpose_v_kernel(
    const u16* __restrict__ src, u16* __restrict__ dst)
{
    __shared__ u16 tile[64][66];
    const int b = blockIdx.z;
    const int n0 = blockIdx.x * 64;   // token dim
    const int k0 = blockIdx.y * 64;   // channel dim
    src += (long)b * (1152L * NTOK) + 768L * NTOK;
    dst += (long)b * (NTOK * 384L);
    const int t = threadIdx.x;
    const int rr = t >> 2, cc4 = (t & 3) * 16;

    const u16* srow = src + (long)(k0 + rr) * NTOK + n0 + cc4;
    uint4 va = *(const uint4*)(srow);
    uint4 vb = *(const uint4*)(srow + 8);
    u32* tp = (u32*)&tile[rr][cc4];
    tp[0] = va.x; tp[1] = va.y; tp[2] = va.z; tp[3] = va.w;
    tp[4] = vb.x; tp[5] = vb.y; tp[6] = vb.z; tp[7] = vb.w;
    __syncthreads();

    char* drow = (char*)dst + (long)(n0 + rr) * (KDIM * 2);
    const int sw = (rr & 7) << 4;
#pragma unroll
    for (int half = 0; half < 2; ++half) {
        u32 pk[4];
#pragma unroll
        for (int i = 0; i < 4; ++i) {
            u16 v0 = tile[cc4 + half*8 + 2*i][rr];
            u16 v1 = tile[cc4 + half*8 + 2*i + 1][rr];
            pk[i] = (u32)v0 | ((u32)v1 << 16);
        }
        uint4 q; q.x = pk[0]; q.y = pk[1]; q.z = pk[2]; q.w = pk[3];
        const int inrow = (k0 + cc4 + half*8) * 2;
        *(uint4*)(drow + (inrow ^ sw)) = q;
    }
}

// ---------------------------------------------------------------------------
// MFMA GEMM: O[b][m][n] = sum_k A[m][k]*B[n][k] (+bias). A,B bf16, rows of
// 384 elems, XOR-swizzled. Tile 128x128, BK=64, 4 waves, dbuf global_load_lds.
// MODE 0: write bf16 plain (qkv). MODE 1: write f32 + bias (final out).
// ---------------------------------------------------------------------------
template<int MODE>
__global__ __launch_bounds__(256) void mfma_gemm(
    const u16* __restrict__ A, long aBatch,
    const u16* __restrict__ Bm, long bBatch,
    void* __restrict__ Ovoid, long oBatch,
    const float* __restrict__ bias)
{
    __shared__ __attribute__((aligned(16))) u16 As[2][128 * 64];
    __shared__ __attribute__((aligned(16))) u16 Bs[2][128 * 64];
    const int b = blockIdx.z;
    const int m0 = blockIdx.x * 128, n0 = blockIdx.y * 128;
    const u16* Ab = A + (long)b * aBatch + (long)m0 * KDIM;
    const u16* Bb = Bm + (long)b * bBatch + (long)n0 * KDIM;
    const int t = threadIdx.x;
    const int w = t >> 6, l = t & 63;
    const int wm = (w >> 1) * 64, wn = (w & 1) * 64;
    const int srow = t >> 3;          // 0..31
    const int scol = (t & 7) * 16;    // byte within 128B row chunk
    f32x4 acc[4][4] = {};

    auto stage = [&](int buf, int kt) {
        const int kbyte = kt * 128;
#pragma unroll
        for (int i = 0; i < 4; ++i) {
            const int row = srow + i * 32;
            const long so = (long)row * 768 + kbyte + scol;
            const int d = (i * 256 + t) * 16;
            __builtin_amdgcn_global_load_lds(
                (const __attribute__((address_space(1))) u32*)((const char*)Ab + so),
                (__attribute__((address_space(3))) u32*)((char*)&As[buf][0] + d), 16, 0, 0);
            __builtin_amdgcn_global_load_lds(
                (const __attribute__((address_space(1))) u32*)((const char*)Bb + so),
                (__attribute__((address_space(3))) u32*)((char*)&Bs[buf][0] + d), 16, 0, 0);
        }
    };

    stage(0, 0);
    __syncthreads();
    int cur = 0;
#pragma unroll 1
    for (int kt = 0; kt < 6; ++kt) {
        if (kt < 5) stage(cur ^ 1, kt + 1);
        const char* Ac = (const char*)&As[cur][0];
        const char* Bc = (const char*)&Bs[cur][0];
#pragma unroll
        for (int kk = 0; kk < 2; ++kk) {
            short8 af[4], bfr[4];
#pragma unroll
            for (int mi = 0; mi < 4; ++mi) {
                const int m = wm + mi * 16 + (l & 15);
                const int off = m * 128 + ((kk * 64 + (l >> 4) * 16) ^ ((m & 7) << 4));
                af[mi] = *(const short8*)(Ac + off);
            }
#pragma unroll
            for (int ni = 0; ni < 4; ++ni) {
                const int n = wn + ni * 16 + (l & 15);
                const int off = n * 128 + ((kk * 64 + (l >> 4) * 16) ^ ((n & 7) << 4));
                bfr[ni] = *(const short8*)(Bc + off);
            }
#pragma unroll
            for (int mi = 0; mi < 4; ++mi)
#pragma unroll
                for (int ni = 0; ni < 4; ++ni)
                    acc[mi][ni] = __builtin_amdgcn_mfma_f32_16x16x32_bf16(
                        af[mi], bfr[ni], acc[mi][ni], 0, 0, 0);
        }
        __syncthreads();
        cur ^= 1;
    }

    if (MODE == 0) {
        u16* O = (u16*)Ovoid + (long)b * oBatch;
#pragma unroll
        for (int mi = 0; mi < 4; ++mi) {
            const int mb = m0 + wm + mi * 16 + (l >> 4) * 4;
#pragma unroll
            for (int ni = 0; ni < 4; ++ni) {
                const int n = n0 + wn + ni * 16 + (l & 15);
#pragma unroll
                for (int r = 0; r < 4; ++r)
                    O[(long)(mb + r) * NTOK + n] = f2bf(acc[mi][ni][r]);
            }
        }
    } else {
        float* O = (float*)Ovoid + (long)b * oBatch;
#pragma unroll
        for (int mi = 0; mi < 4; ++mi) {
            const int mb = m0 + wm + mi * 16 + (l >> 4) * 4;
#pragma unroll
            for (int r = 0; r < 4; ++r) {
                const float bb = bias[mb + r];
#pragma unroll
                for (int ni = 0; ni < 4; ++ni) {
                    const int n = n0 + wn + ni * 16 + (l & 15);
                    O[(long)(mb + r) * NTOK + n] = acc[mi][ni][r] + bb;
                }
            }
        }
    }
}

// ---------------------------------------------------------------------------
// Column L2 norms over n (q: ch 0..383, k: ch 384..767), bf16 input.
// One wave per channel row.
// ---------------------------------------------------------------------------
__global__ __launch_bounds__(256) void colnorm(
    const u16* __restrict__ qkv, float* __restrict__ norms)
{
    const int b = blockIdx.y;
    const int t = threadIdx.x, w = t >> 6, l = t & 63;
    const int ch = blockIdx.x * 4 + w;
    const uint2* row = (const uint2*)(qkv + ((long)b * 1152 + ch) * NTOK);
    float s = 0.f;
#pragma unroll
    for (int i = 0; i < 9; ++i) {
        uint2 vv = row[l + i * 64];
        float a = bf2f(vv.x & 0xffff), c = bf2f(vv.x >> 16);
        float d = bf2f(vv.y & 0xffff), e = bf2f(vv.y >> 16);
        s += a * a + c * c + d * d + e * e;
    }
#pragma unroll
    for (int off = 32; off > 0; off >>= 1) s += __shfl_down(s, off, 64);
    if (l == 0) norms[(long)b * 768 + ch] = fmaxf(sqrtf(s), 1e-12f);
}

// ---------------------------------------------------------------------------
// S partials: per (b,h,chunk) wave computes K[48][192nchunk] . Q[48][..]^T
// via MFMA, operands straight from global (n-contiguous). 12 chunks.
// part[((b*8+h)*12+chunk)][p*48+q]
// ---------------------------------------------------------------------------
__global__ __launch_bounds__(256) void sgemm_partial(
    const u16* __restrict__ qkv, float* __restrict__ part)
{
    const int h = blockIdx.x, b = blockIdx.y;
    const int t = threadIdx.x, w = t >> 6, l = t & 63;
    const int chunk = blockIdx.z * 4 + w;          // 0..11
    const u16* qbase = qkv + ((long)b * 1152 + h * 48) * NTOK;
    const u16* kbase = qbase + 384L * NTOK;
    f32x4 acc[3][3] = {};
    const int lr = l & 15, lk = (l >> 4) * 8;
#pragma unroll 2
    for (int ks = 0; ks < 6; ++ks) {
        const int nn = chunk * 192 + ks * 32 + lk;
        short8 af[3], bfr[3];
#pragma unroll
        for (int mi = 0; mi < 3; ++mi)
            af[mi] = *(const short8*)(kbase + (long)(mi * 16 + lr) * NTOK + nn);
#pragma unroll
        for (int ni = 0; ni < 3; ++ni)
            bfr[ni] = *(const short8*)(qbase + (long)(ni * 16 + lr) * NTOK + nn);
#pragma unroll
        for (int mi = 0; mi < 3; ++mi)
#pragma unroll
            for (int ni = 0; ni < 3; ++ni)
                acc[mi][ni] = __builtin_amdgcn_mfma_f32_16x16x32_bf16(
                    af[mi], bfr[ni], acc[mi][ni], 0, 0, 0);
    }
    float* pb = part + ((long)(b * 8 + h) * 12 + chunk) * 2304;
#pragma unroll
    for (int mi = 0; mi < 3; ++mi)
#pragma unroll
        for (int ni = 0; ni < 3; ++ni)
#pragma unroll
            for (int r = 0; r < 4; ++r) {
                int p = mi * 16 + (l >> 4) * 4 + r;
                int q = ni * 16 + lr;
                pb[p * 48 + q] = acc[mi][ni][r];
            }
}

// ---------------------------------------------------------------------------
// Fold: sum partials -> scale -> softmax -> W2T[j][h*48+p] = sum_q S*w_out
// (bf16, swizzled rows of 384). One block per (b,h).
// ---------------------------------------------------------------------------
__global__ __launch_bounds__(256) void fold_kernel(
    const float* __restrict__ part, const float* __restrict__ norms,
    const float* __restrict__ temp, const float* __restrict__ w_out,
    u16* __restrict__ W2T)
{
    __shared__ float S[48][49];
    __shared__ float wl[48 * 384];
    __shared__ float invq[48], invk[48];
    const int h = blockIdx.x, b = blockIdx.y, t = threadIdx.x;

    const float* pb = part + (long)(b * 8 + h) * 12 * 2304;
    for (int idx = t; idx < 2304; idx += 256) {
        float s = 0.f;
#pragma unroll
        for (int z = 0; z < 12; ++z) s += pb[z * 2304 + idx];
        S[idx / 48][idx % 48] = s;
    }
    if (t < 48) {
        invq[t] = 1.0f / norms[(long)b * 768 + h * 48 + t];
        invk[t] = 1.0f / norms[(long)b * 768 + 384 + h * 48 + t];
    }
    const float4* wsrc = (const float4*)(w_out + (long)h * 48 * 384);
    float4* wd = (float4*)wl;
    for (int idx = t; idx < 48 * 96; idx += 256) wd[idx] = wsrc[idx];
    __syncthreads();

    if (t < 48) {
        const float sc = temp[h] * invk[t];
        float row[48];
        float mx = -1e30f;
#pragma unroll
        for (int q = 0; q < 48; ++q) {
            row[q] = S[t][q] * sc * invq[q];
            mx = fmaxf(mx, row[q]);
        }
        float ssum = 0.f;
#pragma unroll
        for (int q = 0; q < 48; ++q) {
            row[q] = __expf(row[q] - mx);
            ssum += row[q];
        }
        float inv = 1.0f / ssum;
#pragma unroll
        for (int q = 0; q < 48; ++q) S[t][q] = row[q] * inv;
    }
    __syncthreads();

    u16* Wb = W2T + (long)b * 384 * 384;
    for (int idx = t; idx < 384 * 48; idx += 256) {
        int j = idx / 48, p = idx % 48;
        float s = 0.f;
#pragma unroll
        for (int q = 0; q < 48; ++q) s += S[p][q] * wl[q * 384 + j];
        int byteoff = j * 768 + (((h * 48 + p) * 2) ^ ((j & 7) << 4));
        *(u16*)((char*)Wb + byteoff) = f2bf(s);
    }
}

// ---------------------------------------------------------------------------
extern "C" void kernel_launch(void* const* d_in, const int* in_sizes, int n_in,
                              void* d_out, int out_size, void* d_ws, size_t ws_size,
                              hipStream_t stream) {
    const float* x     = (const float*)d_in[0];  // [16][384][2304]
    const float* w_qkv = (const float*)d_in[1];  // [384][1152]
    const float* temp  = (const float*)d_in[2];  // [8]
    const float* w_out = (const float*)d_in[3];  // [384][384]
    const float* b_out = (const float*)d_in[4];  // [384]
    float* out = (float*)d_out;                  // [16][384][2304]

    char* ws = (char*)d_ws;
    const size_t SZ_XT   = 16UL * 2304 * 384 * 2;   // 28.3 MB
    const size_t SZ_QKV  = 16UL * 1152 * 2304 * 2;  // 84.9 MB
    const size_t SZ_VT   = SZ_XT;
    const size_t SZ_WT   = 1152UL * 384 * 2;
    const size_t SZ_NORM = 16UL * 768 * 4;
    const size_t SZ_PART = 16UL * 8 * 12 * 2304 * 4;

    u16*   xT     = (u16*)(ws);
    u16*   qkv    = (u16*)(ws + SZ_XT);
    u16*   vT     = (u16*)(ws + SZ_XT + SZ_QKV);
    u16*   w_qkvT = (u16*)(ws + SZ_XT + SZ_QKV + SZ_VT);
    float* norms  = (float*)(ws + SZ_XT + SZ_QKV + SZ_VT + SZ_WT);
    float* part   = (float*)(ws + SZ_XT + SZ_QKV + SZ_VT + SZ_WT + SZ_NORM);
    u16*   W2T    = (u16*)(ws + SZ_XT + SZ_QKV + SZ_VT + SZ_WT + SZ_NORM + SZ_PART);

    // 1) w_qkv [384][1152] -> w_qkvT [1152][384] bf16 swz
    transpose_f32_to_bf16swz<<<dim3(18, 6, 1), 256, 0, stream>>>(
        w_qkv, 0L, 1152, w_qkvT, 0L);
    // 2) x [b][384][2304] -> xT [b][2304][384] bf16 swz
    transpose_f32_to_bf16swz<<<dim3(36, 6, 16), 256, 0, stream>>>(
        x, 384L * 2304, 2304, xT, 2304L * 384);
    // 3) qkv[b][cc][n] bf16 (plain)
    mfma_gemm<0><<<dim3(9, 18, 16), 256, 0, stream>>>(
        w_qkvT, 0L, xT, 2304L * 384, qkv, 1152L * 2304, nullptr);
    // 4) norms
    colnorm<<<dim3(192, 16), 256, 0, stream>>>(qkv, norms);
    // 5) S partials
    sgemm_partial<<<dim3(8, 16, 3), 256, 0, stream>>>(qkv, part);
    // 6) v -> vT bf16 swz
    transpose_v_kernel<<<dim3(36, 6, 16), 256, 0, stream>>>(qkv, vT);
    // 7) softmax + fold into W2T
    fold_kernel<<<dim3(8, 16), 256, 0, stream>>>(part, norms, temp, w_out, W2T);
    // 8) out[b][j][n] = sum_c W2T[j][c]*vT[n][c] + b_out[j]
    mfma_gemm<1><<<dim3(3, 18, 16), 256, 0, stream>>>(
        W2T, 384L * 384, vT, 2304L * 384, out, 384L * 2304, b_out);
}

// Round 3
// 178.890 us; speedup vs baseline: 4.4419x; 1.2415x over previous
//
#include <hip/hip_runtime.h>
#include <cstdint>

typedef __attribute__((ext_vector_type(8))) short short8;
typedef __attribute__((ext_vector_type(4))) float f32x4;
typedef unsigned int u32;
typedef unsigned short u16;

#define NTOK 2304
#define KDIM 384
#define PSTRIDE 2400   // 2304 S-partial + 48 k-sumsq + 48 q-sumsq

__device__ __forceinline__ u16 f2bf(float f) {
    u32 u = __builtin_bit_cast(u32, f);
    u32 r = (u + 0x7FFFu + ((u >> 16) & 1u)) >> 16;
    return (u16)r;
}
__device__ __forceinline__ float bf2f(u32 h) {
    u32 u = h << 16;
    return __builtin_bit_cast(float, u);
}

// ---------------------------------------------------------------------------
// Transpose + convert: src f32 [K=384][Csz] -> dst bf16 [Csz][384], rows
// XOR-swizzled in 16B chunks: byte' = byte ^ ((row&7)<<4). 64x64 tiles.
// ---------------------------------------------------------------------------
__global__ __launch_bounds__(256) void transpose_f32_to_bf16swz(
    const float* __restrict__ src, long sBatch, int Csz,
    u16* __restrict__ dst, long dBatch)
{
    __shared__ float tile[64][65];
    const int b = blockIdx.z;
    const int c0 = blockIdx.x * 64;   // output-row dim
    const int k0 = blockIdx.y * 64;   // contraction dim (src rows)
    src += (long)b * sBatch;
    dst += (long)b * dBatch;
    const int t = threadIdx.x;
    const int rr = t >> 2, cc4 = (t & 3) * 16;

    const float* srow = src + (long)(k0 + rr) * Csz + c0 + cc4;
#pragma unroll
    for (int i = 0; i < 4; ++i) {
        float4 v = *(const float4*)(srow + i * 4);
        tile[rr][cc4 + i*4 + 0] = v.x;
        tile[rr][cc4 + i*4 + 1] = v.y;
        tile[rr][cc4 + i*4 + 2] = v.z;
        tile[rr][cc4 + i*4 + 3] = v.w;
    }
    __syncthreads();
    char* drow = (char*)dst + (long)(c0 + rr) * (KDIM * 2);
    const int sw = (rr & 7) << 4;
#pragma unroll
    for (int half = 0; half < 2; ++half) {
        u32 pk[4];
#pragma unroll
        for (int i = 0; i < 4; ++i) {
            float v0 = tile[cc4 + half*8 + 2*i][rr];
            float v1 = tile[cc4 + half*8 + 2*i + 1][rr];
            pk[i] = (u32)f2bf(v0) | ((u32)f2bf(v1) << 16);
        }
        uint4 q; q.x = pk[0]; q.y = pk[1]; q.z = pk[2]; q.w = pk[3];
        const int inrow = (k0 + cc4 + half*8) * 2;
        *(uint4*)(drow + (inrow ^ sw)) = q;
    }
}

// ---------------------------------------------------------------------------
// Transpose v (bf16 src): qkv rows 768..1151 [384][2304] -> vT [2304][384] swz
// ---------------------------------------------------------------------------
__global__ __launch_bounds__(256) void transpose_v_kernel(
    const u16* __restrict__ src, u16* __restrict__ dst)
{
    __shared__ u16 tile[64][66];
    const int b = blockIdx.z;
    const int n0 = blockIdx.x * 64;   // token dim
    const int k0 = blockIdx.y * 64;   // channel dim
    src += (long)b * (1152L * NTOK) + 768L * NTOK;
    dst += (long)b * (NTOK * 384L);
    const int t = threadIdx.x;
    const int rr = t >> 2, cc4 = (t & 3) * 16;

    const u16* srow = src + (long)(k0 + rr) * NTOK + n0 + cc4;
    uint4 va = *(const uint4*)(srow);
    uint4 vb = *(const uint4*)(srow + 8);
    u32* tp = (u32*)&tile[rr][cc4];
    tp[0] = va.x; tp[1] = va.y; tp[2] = va.z; tp[3] = va.w;
    tp[4] = vb.x; tp[5] = vb.y; tp[6] = vb.z; tp[7] = vb.w;
    __syncthreads();

    char* drow = (char*)dst + (long)(n0 + rr) * (KDIM * 2);
    const int sw = (rr & 7) << 4;
#pragma unroll
    for (int half = 0; half < 2; ++half) {
        u32 pk[4];
#pragma unroll
        for (int i = 0; i < 4; ++i) {
            u16 v0 = tile[cc4 + half*8 + 2*i][rr];
            u16 v1 = tile[cc4 + half*8 + 2*i + 1][rr];
            pk[i] = (u32)v0 | ((u32)v1 << 16);
        }
        uint4 q; q.x = pk[0]; q.y = pk[1]; q.z = pk[2]; q.w = pk[3];
        const int inrow = (k0 + cc4 + half*8) * 2;
        *(uint4*)(drow + (inrow ^ sw)) = q;
    }
}

// ---------------------------------------------------------------------------
// MFMA GEMM: O[b][m][n] = sum_k A[m][k]*B[n][k] (+bias). A,B bf16, rows of
// 384 elems, XOR-swizzled. Tile 128x128, BK=64, 4 waves, dbuf global_load_lds.
// MODE 0: write bf16 plain (qkv). MODE 1: write f32 + bias (final out).
// ---------------------------------------------------------------------------
template<int MODE>
__global__ __launch_bounds__(256) void mfma_gemm(
    const u16* __restrict__ A, long aBatch,
    const u16* __restrict__ Bm, long bBatch,
    void* __restrict__ Ovoid, long oBatch,
    const float* __restrict__ bias)
{
    __shared__ __attribute__((aligned(16))) u16 As[2][128 * 64];
    __shared__ __attribute__((aligned(16))) u16 Bs[2][128 * 64];
    const int b = blockIdx.z;
    const int m0 = blockIdx.x * 128, n0 = blockIdx.y * 128;
    const u16* Ab = A + (long)b * aBatch + (long)m0 * KDIM;
    const u16* Bb = Bm + (long)b * bBatch + (long)n0 * KDIM;
    const int t = threadIdx.x;
    const int w = t >> 6, l = t & 63;
    const int wm = (w >> 1) * 64, wn = (w & 1) * 64;
    const int srow = t >> 3;          // 0..31
    const int scol = (t & 7) * 16;    // byte within 128B row chunk
    f32x4 acc[4][4] = {};

    auto stage = [&](int buf, int kt) {
        const int kbyte = kt * 128;
#pragma unroll
        for (int i = 0; i < 4; ++i) {
            const int row = srow + i * 32;
            const long so = (long)row * 768 + kbyte + scol;
            const int d = (i * 256 + t) * 16;
            __builtin_amdgcn_global_load_lds(
                (const __attribute__((address_space(1))) u32*)((const char*)Ab + so),
                (__attribute__((address_space(3))) u32*)((char*)&As[buf][0] + d), 16, 0, 0);
            __builtin_amdgcn_global_load_lds(
                (const __attribute__((address_space(1))) u32*)((const char*)Bb + so),
                (__attribute__((address_space(3))) u32*)((char*)&Bs[buf][0] + d), 16, 0, 0);
        }
    };

    stage(0, 0);
    __syncthreads();
    int cur = 0;
#pragma unroll 1
    for (int kt = 0; kt < 6; ++kt) {
        if (kt < 5) stage(cur ^ 1, kt + 1);
        const char* Ac = (const char*)&As[cur][0];
        const char* Bc = (const char*)&Bs[cur][0];
#pragma unroll
        for (int kk = 0; kk < 2; ++kk) {
            short8 af[4], bfr[4];
#pragma unroll
            for (int mi = 0; mi < 4; ++mi) {
                const int m = wm + mi * 16 + (l & 15);
                const int off = m * 128 + ((kk * 64 + (l >> 4) * 16) ^ ((m & 7) << 4));
                af[mi] = *(const short8*)(Ac + off);
            }
#pragma unroll
            for (int ni = 0; ni < 4; ++ni) {
                const int n = wn + ni * 16 + (l & 15);
                const int off = n * 128 + ((kk * 64 + (l >> 4) * 16) ^ ((n & 7) << 4));
                bfr[ni] = *(const short8*)(Bc + off);
            }
#pragma unroll
            for (int mi = 0; mi < 4; ++mi)
#pragma unroll
                for (int ni = 0; ni < 4; ++ni)
                    acc[mi][ni] = __builtin_amdgcn_mfma_f32_16x16x32_bf16(
                        af[mi], bfr[ni], acc[mi][ni], 0, 0, 0);
        }
        __syncthreads();
        cur ^= 1;
    }

    if (MODE == 0) {
        u16* O = (u16*)Ovoid + (long)b * oBatch;
#pragma unroll
        for (int mi = 0; mi < 4; ++mi) {
            const int mb = m0 + wm + mi * 16 + (l >> 4) * 4;
#pragma unroll
            for (int ni = 0; ni < 4; ++ni) {
                const int n = n0 + wn + ni * 16 + (l & 15);
#pragma unroll
                for (int r = 0; r < 4; ++r)
                    O[(long)(mb + r) * NTOK + n] = f2bf(acc[mi][ni][r]);
            }
        }
    } else {
        float* O = (float*)Ovoid + (long)b * oBatch;
#pragma unroll
        for (int mi = 0; mi < 4; ++mi) {
            const int mb = m0 + wm + mi * 16 + (l >> 4) * 4;
#pragma unroll
            for (int r = 0; r < 4; ++r) {
                const float bb = bias[mb + r];
#pragma unroll
                for (int ni = 0; ni < 4; ++ni) {
                    const int n = n0 + wn + ni * 16 + (l & 15);
                    O[(long)(mb + r) * NTOK + n] = acc[mi][ni][r] + bb;
                }
            }
        }
    }
}

// ---------------------------------------------------------------------------
// S partials + row sum-of-squares. Per (b,h,chunk) wave computes
// K[48][192] . Q[48][192]^T via MFMA, operands straight from global.
// Each lane also accumulates sumsq of the elements it loads (each element
// loaded exactly once per chunk); 4-lane shfl reduce -> per-row sumsq.
// part[(b*8+h)*12+chunk]: [0,2304) S (p*48+q), [2304,2352) ksq, [2352,2400) qsq
// ---------------------------------------------------------------------------
__global__ __launch_bounds__(256) void sgemm_partial(
    const u16* __restrict__ qkv, float* __restrict__ part)
{
    const int h = blockIdx.x, b = blockIdx.y;
    const int t = threadIdx.x, w = t >> 6, l = t & 63;
    const int chunk = blockIdx.z * 4 + w;          // 0..11
    const u16* qbase = qkv + ((long)b * 1152 + h * 48) * NTOK;
    const u16* kbase = qbase + 384L * NTOK;
    f32x4 acc[3][3] = {};
    float kss[3] = {0.f, 0.f, 0.f}, qss[3] = {0.f, 0.f, 0.f};
    const int lr = l & 15, lk = (l >> 4) * 8;
#pragma unroll 2
    for (int ks = 0; ks < 6; ++ks) {
        const int nn = chunk * 192 + ks * 32 + lk;
        short8 af[3], bfr[3];
#pragma unroll
        for (int mi = 0; mi < 3; ++mi)
            af[mi] = *(const short8*)(kbase + (long)(mi * 16 + lr) * NTOK + nn);
#pragma unroll
        for (int ni = 0; ni < 3; ++ni)
            bfr[ni] = *(const short8*)(qbase + (long)(ni * 16 + lr) * NTOK + nn);
#pragma unroll
        for (int mi = 0; mi < 3; ++mi)
#pragma unroll
            for (int e = 0; e < 8; ++e) {
                float kv = bf2f((u16)af[mi][e]);
                float qv = bf2f((u16)bfr[mi][e]);
                kss[mi] += kv * kv;
                qss[mi] += qv * qv;
            }
#pragma unroll
        for (int mi = 0; mi < 3; ++mi)
#pragma unroll
            for (int ni = 0; ni < 3; ++ni)
                acc[mi][ni] = __builtin_amdgcn_mfma_f32_16x16x32_bf16(
                    af[mi], bfr[ni], acc[mi][ni], 0, 0, 0);
    }
    float* pb = part + ((long)(b * 8 + h) * 12 + chunk) * PSTRIDE;
#pragma unroll
    for (int mi = 0; mi < 3; ++mi)
#pragma unroll
        for (int ni = 0; ni < 3; ++ni)
#pragma unroll
            for (int r = 0; r < 4; ++r) {
                int p = mi * 16 + (l >> 4) * 4 + r;
                int q = ni * 16 + lr;
                pb[p * 48 + q] = acc[mi][ni][r];
            }
#pragma unroll
    for (int mi = 0; mi < 3; ++mi) {
        kss[mi] += __shfl_xor(kss[mi], 16, 64);
        kss[mi] += __shfl_xor(kss[mi], 32, 64);
        qss[mi] += __shfl_xor(qss[mi], 16, 64);
        qss[mi] += __shfl_xor(qss[mi], 32, 64);
    }
    if (l < 16) {
#pragma unroll
        for (int mi = 0; mi < 3; ++mi) {
            pb[2304 + mi * 16 + lr] = kss[mi];
            pb[2352 + mi * 16 + lr] = qss[mi];
        }
    }
}

// ---------------------------------------------------------------------------
// Sum partials -> norms -> scale -> row softmax -> write probs f32 [48*48].
// One block per (b,h).
// ---------------------------------------------------------------------------
__global__ __launch_bounds__(256) void softmax_kernel(
    const float* __restrict__ part, const float* __restrict__ temp,
    float* __restrict__ Sbuf)
{
    __shared__ float S[48][49];
    __shared__ float ksum[48], qsum[48];
    __shared__ float invk[48], invq[48];
    const int h = blockIdx.x, b = blockIdx.y, t = threadIdx.x;
    const float* pb = part + (long)(b * 8 + h) * 12 * PSTRIDE;
    for (int idx = t; idx < PSTRIDE; idx += 256) {
        float s = 0.f;
#pragma unroll
        for (int z = 0; z < 12; ++z) s += pb[(long)z * PSTRIDE + idx];
        if (idx < 2304) S[idx / 48][idx % 48] = s;
        else if (idx < 2352) ksum[idx - 2304] = s;
        else qsum[idx - 2352] = s;
    }
    __syncthreads();
    if (t < 48) {
        invk[t] = 1.0f / fmaxf(sqrtf(ksum[t]), 1e-12f);
        invq[t] = 1.0f / fmaxf(sqrtf(qsum[t]), 1e-12f);
    }
    __syncthreads();
    if (t < 48) {
        const float sc = temp[h] * invk[t];
        float row[48];
        float mx = -1e30f;
#pragma unroll 8
        for (int q = 0; q < 48; ++q) {
            row[q] = S[t][q] * sc * invq[q];
            mx = fmaxf(mx, row[q]);
        }
        float ssum = 0.f;
#pragma unroll 8
        for (int q = 0; q < 48; ++q) {
            row[q] = __expf(row[q] - mx);
            ssum += row[q];
        }
        float inv = 1.0f / ssum;
#pragma unroll 8
        for (int q = 0; q < 48; ++q) S[t][q] = row[q] * inv;
    }
    __syncthreads();
    float* sp = Sbuf + (long)(b * 8 + h) * 2304;
    for (int idx = t; idx < 2304; idx += 256)
        sp[idx] = S[idx / 48][idx % 48];
}

// ---------------------------------------------------------------------------
// Fold: W2T[b][j][h*48+p] = sum_q S[b,h,p,q] * w_out[h*48+q][j], bf16 swz.
// Grid (6 j-tiles, 8 h, 16 b); each thread 1-2 packed outputs of 8 p's.
// ---------------------------------------------------------------------------
__global__ __launch_bounds__(256) void fold_gemm(
    const float* __restrict__ Sbuf, const float* __restrict__ w_out,
    u16* __restrict__ W2T)
{
    __shared__ float Sl[48][49];
    __shared__ float wl[48][68];
    const int jt = blockIdx.x, h = blockIdx.y, b = blockIdx.z;
    const int t = threadIdx.x;
    const int j0 = jt * 64;
    const float* sp = Sbuf + (long)(b * 8 + h) * 2304;
    for (int idx = t; idx < 2304; idx += 256)
        Sl[idx / 48][idx % 48] = sp[idx];
#pragma unroll
    for (int i = 0; i < 3; ++i) {
        int idx = t + i * 256;   // 0..767
        int q = idx >> 4, c4 = (idx & 15) * 4;
        float4 v = *(const float4*)(w_out + (long)(h * 48 + q) * 384 + j0 + c4);
        *(float4*)&wl[q][c4] = v;
    }
    __syncthreads();
    u16* Wb = W2T + (long)b * 384 * 384;
#pragma unroll
    for (int pass = 0; pass < 2; ++pass) {
        const int wi = t + pass * 256;
        if (wi < 384) {
            const int j = wi & 63, pg = wi >> 6;      // pg 0..5
            float s[8] = {};
#pragma unroll
            for (int q = 0; q < 48; ++q) {
                float wv = wl[q][j];
#pragma unroll
                for (int i = 0; i < 8; ++i) s[i] += Sl[pg * 8 + i][q] * wv;
            }
            u32 pk[4];
#pragma unroll
            for (int i = 0; i < 4; ++i)
                pk[i] = (u32)f2bf(s[2 * i]) | ((u32)f2bf(s[2 * i + 1]) << 16);
            const int jg = j0 + j;
            const int byteoff = jg * 768 +
                (((h * 48 + pg * 8) * 2) ^ ((jg & 7) << 4));
            uint4 qv; qv.x = pk[0]; qv.y = pk[1]; qv.z = pk[2]; qv.w = pk[3];
            *(uint4*)((char*)Wb + byteoff) = qv;
        }
    }
}

// ---------------------------------------------------------------------------
extern "C" void kernel_launch(void* const* d_in, const int* in_sizes, int n_in,
                              void* d_out, int out_size, void* d_ws, size_t ws_size,
                              hipStream_t stream) {
    const float* x     = (const float*)d_in[0];  // [16][384][2304]
    const float* w_qkv = (const float*)d_in[1];  // [384][1152]
    const float* temp  = (const float*)d_in[2];  // [8]
    const float* w_out = (const float*)d_in[3];  // [384][384]
    const float* b_out = (const float*)d_in[4];  // [384]
    float* out = (float*)d_out;                  // [16][384][2304]

    char* ws = (char*)d_ws;
    const size_t SZ_XT   = 16UL * 2304 * 384 * 2;        // 28.3 MB
    const size_t SZ_QKV  = 16UL * 1152 * 2304 * 2;       // 84.9 MB
    const size_t SZ_VT   = SZ_XT;                        // 28.3 MB
    const size_t SZ_WT   = 1152UL * 384 * 2;             // 0.88 MB
    const size_t SZ_PART = 16UL * 8 * 12 * PSTRIDE * 4;  // 14.7 MB
    const size_t SZ_SB   = 16UL * 8 * 2304 * 4;          // 1.18 MB

    u16*   xT     = (u16*)(ws);
    u16*   qkv    = (u16*)(ws + SZ_XT);
    u16*   vT     = (u16*)(ws + SZ_XT + SZ_QKV);
    u16*   w_qkvT = (u16*)(ws + SZ_XT + SZ_QKV + SZ_VT);
    float* part   = (float*)(ws + SZ_XT + SZ_QKV + SZ_VT + SZ_WT);
    float* Sbuf   = (float*)(ws + SZ_XT + SZ_QKV + SZ_VT + SZ_WT + SZ_PART);
    u16*   W2T    = (u16*)(ws + SZ_XT + SZ_QKV + SZ_VT + SZ_WT + SZ_PART + SZ_SB);

    // 1) w_qkv [384][1152] -> w_qkvT [1152][384] bf16 swz
    transpose_f32_to_bf16swz<<<dim3(18, 6, 1), 256, 0, stream>>>(
        w_qkv, 0L, 1152, w_qkvT, 0L);
    // 2) x [b][384][2304] -> xT [b][2304][384] bf16 swz
    transpose_f32_to_bf16swz<<<dim3(36, 6, 16), 256, 0, stream>>>(
        x, 384L * 2304, 2304, xT, 2304L * 384);
    // 3) qkv[b][cc][n] bf16 (plain)
    mfma_gemm<0><<<dim3(9, 18, 16), 256, 0, stream>>>(
        w_qkvT, 0L, xT, 2304L * 384, qkv, 1152L * 2304, nullptr);
    // 4) S partials + row sumsq
    sgemm_partial<<<dim3(8, 16, 3), 256, 0, stream>>>(qkv, part);
    // 5) v -> vT bf16 swz
    transpose_v_kernel<<<dim3(36, 6, 16), 256, 0, stream>>>(qkv, vT);
    // 6) norms + softmax -> probs
    softmax_kernel<<<dim3(8, 16), 256, 0, stream>>>(part, temp, Sbuf);
    // 7) fold probs into output projection (bf16 swz)
    fold_gemm<<<dim3(6, 8, 16), 256, 0, stream>>>(Sbuf, w_out, W2T);
    // 8) out[b][j][n] = sum_c W2T[j][c]*vT[n][c] + b_out[j]
    mfma_gemm<1><<<dim3(3, 18, 16), 256, 0, stream>>>(
        W2T, 384L * 384, vT, 2304L * 384, out, 384L * 2304, b_out);
}

// Round 4
// 133.469 us; speedup vs baseline: 5.9535x; 1.3403x over previous
//
#include <hip/hip_runtime.h>
#include <cstdint>

typedef __attribute__((ext_vector_type(8))) short short8;
typedef __attribute__((ext_vector_type(4))) float f32x4;
typedef unsigned int u32;
typedef unsigned short u16;

#define NTOK 2304
#define CDIM 384

__device__ __forceinline__ u16 f2bf(float f) {
    u32 u = __builtin_bit_cast(u32, f);
    u32 r = (u + 0x7FFFu + ((u >> 16) & 1u)) >> 16;
    return (u16)r;
}
__device__ __forceinline__ float bf2f(u32 h) {
    u32 u = h << 16;
    return __builtin_bit_cast(float, u);
}

// ---------------------------------------------------------------------------
// Transpose + convert with optional dual output.
// src f32 [384 rows (c)][Csz cols] -> dstT bf16 [Csz][384] swz (rows = cols of src)
//                                  -> dstC bf16 [384][Csz]  swz (cast only), if non-null
// swizzle: byte' = byte ^ ((row&7)<<4) on 16B chunks within each row.
// ---------------------------------------------------------------------------
__global__ __launch_bounds__(256) void transpose_dual(
    const float* __restrict__ src, long sBatch, int Csz,
    u16* __restrict__ dstT, long dtBatch,
    u16* __restrict__ dstC, long dcBatch)
{
    __shared__ float tile[64][65];
    const int b = blockIdx.z;
    const int c0 = blockIdx.x * 64;   // col-tile of src
    const int k0 = blockIdx.y * 64;   // row-tile of src (c)
    src += (long)b * sBatch;
    const int t = threadIdx.x;
    const int rr = t >> 2, cc4 = (t & 3) * 16;

    const float* srow = src + (long)(k0 + rr) * Csz + c0 + cc4;
#pragma unroll
    for (int i = 0; i < 4; ++i) {
        float4 v = *(const float4*)(srow + i * 4);
        tile[rr][cc4 + i*4 + 0] = v.x;
        tile[rr][cc4 + i*4 + 1] = v.y;
        tile[rr][cc4 + i*4 + 2] = v.z;
        tile[rr][cc4 + i*4 + 3] = v.w;
    }
    __syncthreads();

    // transposed output: rows = c0+rr (src cols), length 384
    {
        char* drow = (char*)(dstT + (long)b * dtBatch) + (long)(c0 + rr) * (CDIM * 2);
        const int sw = (rr & 7) << 4;
#pragma unroll
        for (int half = 0; half < 2; ++half) {
            u32 pk[4];
#pragma unroll
            for (int i = 0; i < 4; ++i) {
                float v0 = tile[cc4 + half*8 + 2*i][rr];
                float v1 = tile[cc4 + half*8 + 2*i + 1][rr];
                pk[i] = (u32)f2bf(v0) | ((u32)f2bf(v1) << 16);
            }
            uint4 q; q.x = pk[0]; q.y = pk[1]; q.z = pk[2]; q.w = pk[3];
            const int inrow = (k0 + cc4 + half*8) * 2;
            *(uint4*)(drow + (inrow ^ sw)) = q;
        }
    }
    // cast output: rows = k0+rr (src rows, c), length Csz
    if (dstC) {
        char* drow = (char*)(dstC + (long)b * dcBatch) + (long)(k0 + rr) * ((long)Csz * 2);
        const int sw = (rr & 7) << 4;
#pragma unroll
        for (int half = 0; half < 2; ++half) {
            u32 pk[4];
#pragma unroll
            for (int i = 0; i < 4; ++i) {
                float v0 = tile[rr][cc4 + half*8 + 2*i];
                float v1 = tile[rr][cc4 + half*8 + 2*i + 1];
                pk[i] = (u32)f2bf(v0) | ((u32)f2bf(v1) << 16);
            }
            uint4 q; q.x = pk[0]; q.y = pk[1]; q.z = pk[2]; q.w = pk[3];
            const int inrow = (c0 + cc4 + half*8) * 2;
            *(uint4*)(drow + (inrow ^ sw)) = q;
        }
    }
}

// ---------------------------------------------------------------------------
// Cast w_qkv v-columns: Wv[c][cc] = w_qkv[c][768+cc] f32 -> bf16 [384][384] swz
// ---------------------------------------------------------------------------
__global__ __launch_bounds__(256) void cast_wv(
    const float* __restrict__ w_qkv, u16* __restrict__ dst)
{
    const int idx = blockIdx.x * 256 + threadIdx.x;   // 0..18431
    const int c = idx / 48, ch = (idx % 48) * 8;
    const float* s = w_qkv + (long)c * 1152 + 768 + ch;
    float4 a = *(const float4*)s;
    float4 b = *(const float4*)(s + 4);
    uint4 q;
    q.x = (u32)f2bf(a.x) | ((u32)f2bf(a.y) << 16);
    q.y = (u32)f2bf(a.z) | ((u32)f2bf(a.w) << 16);
    q.z = (u32)f2bf(b.x) | ((u32)f2bf(b.y) << 16);
    q.w = (u32)f2bf(b.z) | ((u32)f2bf(b.w) << 16);
    *(uint4*)((char*)dst + (long)c * 768 + ((ch * 2) ^ ((c & 7) << 4))) = q;
}

// ---------------------------------------------------------------------------
// Generalized MFMA GEMM: O[b][m][n] = sum_k A[m][k]*B[n][k] (+bias).
// A,B bf16 rows of KT*64 elems, XOR-swizzled. 128x128 tile, BK=64, 4 waves,
// dbuf global_load_lds. XCD-aware bijective block swizzle (NWG % 8 == 0).
// MODE 0: bf16 plain; MODE 1: f32 + bias; MODE 2: bf16 swizzled rows.
// ---------------------------------------------------------------------------
template<int MODE, int KT, int GX, int GY>
__global__ __launch_bounds__(256) void mfma_gemm(
    const u16* __restrict__ A, long aBatch,
    const u16* __restrict__ Bm, long bBatch,
    void* __restrict__ Ovoid, long oBatch, int ostride,
    const float* __restrict__ bias)
{
    constexpr int KB  = KT * 128;   // row bytes
    constexpr int KE  = KT * 64;    // row elems
    constexpr int NWG = GX * GY * 16;
    __shared__ __attribute__((aligned(16))) u16 As[2][128 * 64];
    __shared__ __attribute__((aligned(16))) u16 Bs[2][128 * 64];

    const int lid = blockIdx.x + GX * (blockIdx.y + GY * blockIdx.z);
    const int swzid = (lid & 7) * (NWG / 8) + (lid >> 3);
    const int b   = swzid / (GX * GY);
    const int rem = swzid % (GX * GY);
    const int m0 = (rem % GX) * 128, n0 = (rem / GX) * 128;

    const u16* Ab = A + (long)b * aBatch + (long)m0 * KE;
    const u16* Bb = Bm + (long)b * bBatch + (long)n0 * KE;
    const int t = threadIdx.x;
    const int w = t >> 6, l = t & 63;
    const int wm = (w >> 1) * 64, wn = (w & 1) * 64;
    const int srow = t >> 3;          // 0..31
    const int scol = (t & 7) * 16;    // byte within 128B row chunk
    f32x4 acc[4][4] = {};

    auto stage = [&](int buf, int kt) {
        const int kbyte = kt * 128;
#pragma unroll
        for (int i = 0; i < 4; ++i) {
            const int row = srow + i * 32;
            const long so = (long)row * KB + kbyte + scol;
            const int d = (i * 256 + t) * 16;
            __builtin_amdgcn_global_load_lds(
                (const __attribute__((address_space(1))) u32*)((const char*)Ab + so),
                (__attribute__((address_space(3))) u32*)((char*)&As[buf][0] + d), 16, 0, 0);
            __builtin_amdgcn_global_load_lds(
                (const __attribute__((address_space(1))) u32*)((const char*)Bb + so),
                (__attribute__((address_space(3))) u32*)((char*)&Bs[buf][0] + d), 16, 0, 0);
        }
    };

    stage(0, 0);
    __syncthreads();
    int cur = 0;
#pragma unroll 1
    for (int kt = 0; kt < KT; ++kt) {
        if (kt < KT - 1) stage(cur ^ 1, kt + 1);
        const char* Ac = (const char*)&As[cur][0];
        const char* Bc = (const char*)&Bs[cur][0];
#pragma unroll
        for (int kk = 0; kk < 2; ++kk) {
            short8 af[4], bfr[4];
#pragma unroll
            for (int mi = 0; mi < 4; ++mi) {
                const int m = wm + mi * 16 + (l & 15);
                const int off = m * 128 + ((kk * 64 + (l >> 4) * 16) ^ ((m & 7) << 4));
                af[mi] = *(const short8*)(Ac + off);
            }
#pragma unroll
            for (int ni = 0; ni < 4; ++ni) {
                const int n = wn + ni * 16 + (l & 15);
                const int off = n * 128 + ((kk * 64 + (l >> 4) * 16) ^ ((n & 7) << 4));
                bfr[ni] = *(const short8*)(Bc + off);
            }
#pragma unroll
            for (int mi = 0; mi < 4; ++mi)
#pragma unroll
                for (int ni = 0; ni < 4; ++ni)
                    acc[mi][ni] = __builtin_amdgcn_mfma_f32_16x16x32_bf16(
                        af[mi], bfr[ni], acc[mi][ni], 0, 0, 0);
        }
        __syncthreads();
        cur ^= 1;
    }

    if (MODE == 0) {
        u16* O = (u16*)Ovoid + (long)b * oBatch;
#pragma unroll
        for (int mi = 0; mi < 4; ++mi) {
            const int mb = m0 + wm + mi * 16 + (l >> 4) * 4;
#pragma unroll
            for (int ni = 0; ni < 4; ++ni) {
                const int n = n0 + wn + ni * 16 + (l & 15);
#pragma unroll
                for (int r = 0; r < 4; ++r)
                    O[(long)(mb + r) * ostride + n] = f2bf(acc[mi][ni][r]);
            }
        }
    } else if (MODE == 1) {
        float* O = (float*)Ovoid + (long)b * oBatch;
#pragma unroll
        for (int mi = 0; mi < 4; ++mi) {
            const int mb = m0 + wm + mi * 16 + (l >> 4) * 4;
#pragma unroll
            for (int r = 0; r < 4; ++r) {
                const float bb = bias[mb + r];
#pragma unroll
                for (int ni = 0; ni < 4; ++ni) {
                    const int n = n0 + wn + ni * 16 + (l & 15);
                    O[(long)(mb + r) * ostride + n] = acc[mi][ni][r] + bb;
                }
            }
        }
    } else {
        char* Ob = (char*)Ovoid + (long)b * oBatch * 2;
#pragma unroll
        for (int mi = 0; mi < 4; ++mi) {
            const int mb = m0 + wm + mi * 16 + (l >> 4) * 4;
#pragma unroll
            for (int ni = 0; ni < 4; ++ni) {
                const int n = n0 + wn + ni * 16 + (l & 15);
#pragma unroll
                for (int r = 0; r < 4; ++r) {
                    const int m = mb + r;
                    const long byteoff = (long)m * (ostride * 2) +
                        (((long)n * 2) ^ ((m & 7) << 4));
                    *(u16*)(Ob + byteoff) = f2bf(acc[mi][ni][r]);
                }
            }
        }
    }
}

// ---------------------------------------------------------------------------
// Per (b,h): S[p][q] = sum_c T'[384+h48+p][c] * wT[h48+q][c]  (MFMA, k-split 4)
// norms from diagonals; scale by temp/(|k||q|); row softmax -> Sbuf f32.
// ---------------------------------------------------------------------------
__global__ __launch_bounds__(256) void s_softmax(
    const u16* __restrict__ Tp,    // [16][768][384] plain bf16
    const u16* __restrict__ wT,    // [1152][384] swz bf16
    const float* __restrict__ temp, float* __restrict__ Sbuf)
{
    __shared__ float Sp[4][48][48];
    __shared__ float S[48][49];
    __shared__ float invk[48], invq[48];
    const int h = blockIdx.x, b = blockIdx.y, t = threadIdx.x;
    const int w = t >> 6, l = t & 63, lr = l & 15, lk = (l >> 4) * 8;

    const u16* Tk = Tp + ((long)b * 768 + 384 + h * 48) * CDIM;
    f32x4 acc[3][3] = {};
#pragma unroll
    for (int ks = 0; ks < 3; ++ks) {
        const int k0 = w * 96 + ks * 32 + lk;
        short8 af[3], bfr[3];
#pragma unroll
        for (int mi = 0; mi < 3; ++mi)
            af[mi] = *(const short8*)(Tk + (long)(mi * 16 + lr) * CDIM + k0);
#pragma unroll
        for (int ni = 0; ni < 3; ++ni) {
            const int row = h * 48 + ni * 16 + lr;
            const char* base = (const char*)wT + (long)row * 768;
            bfr[ni] = *(const short8*)(base + ((k0 * 2) ^ ((row & 7) << 4)));
        }
#pragma unroll
        for (int mi = 0; mi < 3; ++mi)
#pragma unroll
            for (int ni = 0; ni < 3; ++ni)
                acc[mi][ni] = __builtin_amdgcn_mfma_f32_16x16x32_bf16(
                    af[mi], bfr[ni], acc[mi][ni], 0, 0, 0);
    }
#pragma unroll
    for (int mi = 0; mi < 3; ++mi)
#pragma unroll
        for (int ni = 0; ni < 3; ++ni)
#pragma unroll
            for (int r = 0; r < 4; ++r)
                Sp[w][mi * 16 + (l >> 4) * 4 + r][ni * 16 + lr] = acc[mi][ni][r];
    // norms: t<48 -> q channel h48+t ; t in [48,96) -> k channel 384+h48+(t-48)
    if (t < 96) {
        const int ch = (t < 48) ? (h * 48 + t) : (384 + h * 48 + (t - 48));
        const u16* trow = Tp + ((long)b * 768 + ch) * CDIM;
        const char* wrow = (const char*)wT + (long)ch * 768;
        const int sw = (ch & 7) << 4;
        float s = 0.f;
#pragma unroll 4
        for (int i = 0; i < 48; ++i) {
            short8 tv = *(const short8*)(trow + i * 8);
            short8 wv = *(const short8*)(wrow + ((i * 16) ^ sw));
#pragma unroll
            for (int e = 0; e < 8; ++e)
                s += bf2f((u16)tv[e]) * bf2f((u16)wv[e]);
        }
        float inv = 1.0f / fmaxf(sqrtf(fmaxf(s, 0.f)), 1e-12f);
        if (t < 48) invq[t] = inv; else invk[t - 48] = inv;
    }
    __syncthreads();
    for (int idx = t; idx < 2304; idx += 256) {
        const int p = idx / 48, q = idx % 48;
        S[p][q] = Sp[0][p][q] + Sp[1][p][q] + Sp[2][p][q] + Sp[3][p][q];
    }
    __syncthreads();
    if (t < 48) {
        const float sc = temp[h] * invk[t];
        float row[48];
        float mx = -1e30f;
#pragma unroll 8
        for (int q = 0; q < 48; ++q) {
            row[q] = S[t][q] * sc * invq[q];
            mx = fmaxf(mx, row[q]);
        }
        float ssum = 0.f;
#pragma unroll 8
        for (int q = 0; q < 48; ++q) {
            row[q] = __expf(row[q] - mx);
            ssum += row[q];
        }
        float inv = 1.0f / ssum;
#pragma unroll 8
        for (int q = 0; q < 48; ++q) S[t][q] = row[q] * inv;
    }
    __syncthreads();
    float* sp = Sbuf + (long)(b * 8 + h) * 2304;
    for (int idx = t; idx < 2304; idx += 256)
        sp[idx] = S[idx / 48][idx % 48];
}

// ---------------------------------------------------------------------------
// Fold: W2T[b][j][h*48+p] = sum_q S[b,h,p,q] * w_out[h*48+q][j], bf16 swz.
// ---------------------------------------------------------------------------
__global__ __launch_bounds__(256) void fold_gemm(
    const float* __restrict__ Sbuf, const float* __restrict__ w_out,
    u16* __restrict__ W2T)
{
    __shared__ float Sl[48][49];
    __shared__ float wl[48][68];
    const int jt = blockIdx.x, h = blockIdx.y, b = blockIdx.z;
    const int t = threadIdx.x;
    const int j0 = jt * 64;
    const float* sp = Sbuf + (long)(b * 8 + h) * 2304;
    for (int idx = t; idx < 2304; idx += 256)
        Sl[idx / 48][idx % 48] = sp[idx];
#pragma unroll
    for (int i = 0; i < 3; ++i) {
        int idx = t + i * 256;   // 0..767
        int q = idx >> 4, c4 = (idx & 15) * 4;
        float4 v = *(const float4*)(w_out + (long)(h * 48 + q) * 384 + j0 + c4);
        *(float4*)&wl[q][c4] = v;
    }
    __syncthreads();
    u16* Wb = W2T + (long)b * 384 * 384;
#pragma unroll
    for (int pass = 0; pass < 2; ++pass) {
        const int wi = t + pass * 256;
        if (wi < 384) {
            const int j = wi & 63, pg = wi >> 6;      // pg 0..5
            float s[8] = {};
#pragma unroll
            for (int q = 0; q < 48; ++q) {
                float wv = wl[q][j];
#pragma unroll
                for (int i = 0; i < 8; ++i) s[i] += Sl[pg * 8 + i][q] * wv;
            }
            u32 pk[4];
#pragma unroll
            for (int i = 0; i < 4; ++i)
                pk[i] = (u32)f2bf(s[2 * i]) | ((u32)f2bf(s[2 * i + 1]) << 16);
            const int jg = j0 + j;
            const int byteoff = jg * 768 +
                (((h * 48 + pg * 8) * 2) ^ ((jg & 7) << 4));
            uint4 qv; qv.x = pk[0]; qv.y = pk[1]; qv.z = pk[2]; qv.w = pk[3];
            *(uint4*)((char*)Wb + byteoff) = qv;
        }
    }
}

// ---------------------------------------------------------------------------
extern "C" void kernel_launch(void* const* d_in, const int* in_sizes, int n_in,
                              void* d_out, int out_size, void* d_ws, size_t ws_size,
                              hipStream_t stream) {
    const float* x     = (const float*)d_in[0];  // [16][384][2304]
    const float* w_qkv = (const float*)d_in[1];  // [384][1152]
    const float* temp  = (const float*)d_in[2];  // [8]
    const float* w_out = (const float*)d_in[3];  // [384][384]
    const float* b_out = (const float*)d_in[4];  // [384]
    float* out = (float*)d_out;                  // [16][384][2304]

    char* ws = (char*)d_ws;
    const size_t SZ_XBF = 16UL * 384 * 2304 * 2;   // 28.3 MB
    const size_t SZ_XT  = 16UL * 2304 * 384 * 2;   // 28.3 MB
    const size_t SZ_WQT = 1152UL * 384 * 2;        // 0.88 MB
    const size_t SZ_WV  = 384UL * 384 * 2;         // 0.29 MB
    const size_t SZ_G   = 16UL * 384 * 384 * 2;    // 4.7 MB
    const size_t SZ_TP  = 16UL * 768 * 384 * 2;    // 9.4 MB
    const size_t SZ_SB  = 16UL * 8 * 2304 * 4;     // 1.2 MB
    const size_t SZ_W2  = 16UL * 384 * 384 * 2;    // 4.7 MB

    size_t off = 0;
    u16*   xbf   = (u16*)(ws + off); off += SZ_XBF;
    u16*   xT    = (u16*)(ws + off); off += SZ_XT;
    u16*   wqkvT = (u16*)(ws + off); off += SZ_WQT;
    u16*   wv    = (u16*)(ws + off); off += SZ_WV;
    u16*   Gs    = (u16*)(ws + off); off += SZ_G;
    u16*   Tp    = (u16*)(ws + off); off += SZ_TP;
    float* Sbuf  = (float*)(ws + off); off += SZ_SB;
    u16*   W2T   = (u16*)(ws + off); off += SZ_W2;
    u16*   W3    = (u16*)(ws + off);

    // 1) x -> xT [n][c] swz AND xbf [c][n] swz (one read of x)
    transpose_dual<<<dim3(36, 6, 16), 256, 0, stream>>>(
        x, 384L * 2304, 2304, xT, 2304L * 384, xbf, 384L * 2304);
    // 2) w_qkv -> wqkvT [1152][384] swz
    transpose_dual<<<dim3(18, 6, 1), 256, 0, stream>>>(
        w_qkv, 0L, 1152, wqkvT, 0L, nullptr, 0L);
    // 3) Wv cast [384 c][384 cc] swz
    cast_wv<<<72, 256, 0, stream>>>(w_qkv, wv);
    // 4) G[b] = X X^T  (bf16 swz out)
    mfma_gemm<2, 36, 3, 3><<<dim3(3, 3, 16), 256, 0, stream>>>(
        xbf, 384L * 2304, xbf, 384L * 2304, Gs, 384L * 384, 384, nullptr);
    // 5) T'[b] = W_qk^T G  (plain bf16 out [768][384])
    mfma_gemm<0, 6, 6, 3><<<dim3(6, 3, 16), 256, 0, stream>>>(
        wqkvT, 0L, Gs, 384L * 384, Tp, 768L * 384, 384, nullptr);
    // 6) S + norms + softmax -> Sbuf
    s_softmax<<<dim3(8, 16), 256, 0, stream>>>(Tp, wqkvT, temp, Sbuf);
    // 7) fold probs into w_out -> W2T swz
    fold_gemm<<<dim3(6, 8, 16), 256, 0, stream>>>(Sbuf, w_out, W2T);
    // 8) W3[b] = W2^T Wv  (bf16 swz out)
    mfma_gemm<2, 6, 3, 3><<<dim3(3, 3, 16), 256, 0, stream>>>(
        W2T, 384L * 384, wv, 0L, W3, 384L * 384, 384, nullptr);
    // 9) out[b] = W3 X + b_out  (f32)
    mfma_gemm<1, 6, 3, 18><<<dim3(3, 18, 16), 256, 0, stream>>>(
        W3, 384L * 384, xT, 384L * 2304, out, 384L * 2304, 2304, b_out);
}